// Round 4
// baseline (39.485 us; speedup 1.0000x reference)
//
#include <hip/hip_runtime.h>

typedef __attribute__((ext_vector_type(8))) short short8;
typedef __attribute__((ext_vector_type(4))) float f32x4;

#define NROWS 32768        // B*H*W
#define NELEM 262144       // B*C*H*W
#define KCB   8192
#define ROWS_PB 128        // rows per block
#define NWAVE 16           // k-waves per block; each scans KCB/16 = 512 entries

// round-to-nearest-even fp32 -> bf16 (finite values only)
static __device__ __forceinline__ short to_bf16(float x) {
    unsigned u = __float_as_uint(x);
    unsigned r = (u + 0x7FFFu + ((u >> 16) & 1u)) >> 16;
    return (short)r;
}

// Prep: pack codebook entries as 16 bf16 [e0..e7, -0.5*||e||^2, 0...] and
// z rows as 8 bf16; zero the loss slot.
__global__ __launch_bounds__(256) void vq_prep(
    const float* __restrict__ z, const float* __restrict__ cb,
    short8* __restrict__ cbb, short8* __restrict__ pka, float* __restrict__ out)
{
    int gid = blockIdx.x * 256 + threadIdx.x;
    if (gid == 0) out[NELEM] = 0.0f;
    if (gid < KCB) {
        const float4* p = (const float4*)(cb + (size_t)gid * 8);
        float4 a = p[0], b = p[1];
        float h = -0.5f * (a.x*a.x + a.y*a.y + a.z*a.z + a.w*a.w
                         + b.x*b.x + b.y*b.y + b.z*b.z + b.w*b.w);
        short8 lo = { to_bf16(a.x), to_bf16(a.y), to_bf16(a.z), to_bf16(a.w),
                      to_bf16(b.x), to_bf16(b.y), to_bf16(b.z), to_bf16(b.w) };
        short8 hi = { to_bf16(h), 0, 0, 0, 0, 0, 0, 0 };
        cbb[2 * gid]     = lo;
        cbb[2 * gid + 1] = hi;
    } else {
        int n = gid - KCB;
        int bb = n >> 12, hw = n & 4095;
        const float* zp = z + (size_t)bb * 32768 + hw;
        short8 v = { to_bf16(zp[0]),     to_bf16(zp[4096]),
                     to_bf16(zp[8192]),  to_bf16(zp[12288]),
                     to_bf16(zp[16384]), to_bf16(zp[20480]),
                     to_bf16(zp[24576]), to_bf16(zp[28672]) };
        pka[n] = v;
    }
}

// Main: 256 blocks x 1024 thr (16 waves), 128 rows/block. Wave w scans a
// private 512-entry k-range straight global(L2)->VGPR, depth-2 prefetched.
// Each B-load feeds 8 MFMAs (8 row-tiles). Argmax = packed (score|inv-idx)
// + v_max (2 VALU/score).
__global__ __launch_bounds__(1024, 4) void vq_main(
    const float* __restrict__ z, const float* __restrict__ cb,
    const short8* __restrict__ cbb, const short8* __restrict__ pka,
    float* __restrict__ out)
{
    __shared__ float sbest[NWAVE][ROWS_PB];
    __shared__ float lsum[NWAVE];

    const int tid  = threadIdx.x;
    const int lane = tid & 63;
    const int w    = tid >> 6;        // k-wave 0..15
    const int col  = lane & 15;
    const int g    = lane >> 4;

    const int row0 = blockIdx.x * ROWS_PB;

    // ---- A fragments: 8 row-tiles of 16; k-slots 0..7 = channels, 8 = 1.0 ----
    short8 af[8];
    #pragma unroll
    for (int f = 0; f < 8; ++f) {
        short8 v = {0, 0, 0, 0, 0, 0, 0, 0};
        if (g == 0)      v = pka[row0 + f * 16 + col];
        else if (g == 1) v[0] = (short)0x3F80;   // bf16(1.0) pairs with -0.5||e||^2
        af[f] = v;
    }

    const int kbase = w * (KCB / NWAVE);         // 512-entry range
    const char* bpc = (const char*)cbb + (size_t)(kbase + col) * 32
                                       + (size_t)(g & 1) * 16;

    float best[8][4];
    #pragma unroll
    for (int f = 0; f < 8; ++f)
        #pragma unroll
        for (int r = 0; r < 4; ++r)
            best[f][r] = __uint_as_float(0xFF800000u);   // -inf

    const unsigned inv0 = (unsigned)(8191 - (kbase + col));
    const f32x4 zacc = {0.f, 0.f, 0.f, 0.f};

#define LDT(T) (*(const short8*)(bpc + (size_t)(T) * 512))

    auto comp = [&](short8 bf, int t) {
        unsigned iv = inv0 - (unsigned)(t * 16);
        #pragma unroll
        for (int f = 0; f < 8; ++f) {
            f32x4 acc = __builtin_amdgcn_mfma_f32_16x16x32_bf16(af[f], bf, zacc, 0, 0, 0);
            #pragma unroll
            for (int r = 0; r < 4; ++r) {
                float p = __uint_as_float((__float_as_uint(acc[r]) & 0xFFFFE000u) | iv);
                best[f][r] = fmaxf(best[f][r], p);
            }
        }
    };

    // ---- 32 tiles of 16 entries, depth-2 register prefetch ----
    short8 c0 = LDT(0);
    short8 c1 = LDT(1);
    #pragma unroll
    for (int tt = 0; tt < 16; ++tt) {
        short8 n0, n1;
        if (tt < 15) { n0 = LDT(2 * tt + 2); n1 = LDT(2 * tt + 3); }
        comp(c0, 2 * tt);
        comp(c1, 2 * tt + 1);
        if (tt < 15) { c0 = n0; c1 = n1; }
    }

    // ---- cross-lane max within each 16-lane col group ----
    #pragma unroll
    for (int d = 1; d < 16; d <<= 1)
        #pragma unroll
        for (int f = 0; f < 8; ++f)
            #pragma unroll
            for (int r = 0; r < 4; ++r)
                best[f][r] = fmaxf(best[f][r], __shfl_xor(best[f][r], d));

    if (col == 0) {
        #pragma unroll
        for (int f = 0; f < 8; ++f)
            #pragma unroll
            for (int r = 0; r < 4; ++r)
                sbest[w][f * 16 + g * 4 + r] = best[f][r];   // row = g*4+r of tile f
    }
    __syncthreads();

    // ---- emit: 128 rows x 8 ch, one elem/thread ----
    const int pos = tid & 127;
    const int ch  = tid >> 7;
    float m = sbest[0][pos];
    #pragma unroll
    for (int kw = 1; kw < NWAVE; ++kw) m = fmaxf(m, sbest[kw][pos]);
    const int k = 8191 - (int)(__float_as_uint(m) & 8191u);

    const int n = row0 + pos;
    const size_t o = ((size_t)(n >> 12)) * 32768 + (size_t)ch * 4096 + (size_t)(n & 4095);
    float ev = cb[(size_t)k * 8 + ch];
    float zz = z[o];
    out[o] = ev;
    float dd = ev - zz;
    float sq = dd * dd;
    #pragma unroll
    for (int off = 32; off > 0; off >>= 1) sq += __shfl_down(sq, off);
    if (lane == 0) lsum[w] = sq;
    __syncthreads();
    if (tid == 0) {
        float s = 0.f;
        #pragma unroll
        for (int kw = 0; kw < NWAVE; ++kw) s += lsum[kw];
        atomicAdd(out + NELEM, s * (1.25f / (float)NELEM));
    }
}

extern "C" void kernel_launch(void* const* d_in, const int* in_sizes, int n_in,
                              void* d_out, int out_size, void* d_ws, size_t ws_size,
                              hipStream_t stream)
{
    const float* z  = (const float*)d_in[0];   // [8, 8, 64, 64] fp32
    const float* cb = (const float*)d_in[1];   // [8192, 8] fp32
    float* out = (float*)d_out;                // 262144 z_q + 1 loss
    short8* cbb = (short8*)d_ws;                       // 256 KB packed codebook
    short8* pka = (short8*)((char*)d_ws + 256 * 1024); // 512 KB packed z rows

    vq_prep<<<(KCB + NROWS) / 256, 256, 0, stream>>>(z, cb, cbb, pka, out);
    vq_main<<<NROWS / ROWS_PB, 1024, 0, stream>>>(z, cb, cbb, pka, out);
}

// Round 5
// 34.547 us; speedup vs baseline: 1.1429x; 1.1429x over previous
//
#include <hip/hip_runtime.h>

typedef __attribute__((ext_vector_type(8))) short short8;
typedef __attribute__((ext_vector_type(4))) float f32x4;

#define NROWS 32768        // B*H*W
#define NELEM 262144       // B*C*H*W
#define KCB   8192
#define ROWS_PB 64
#define RING  4            // pairs in flight per wave (1 pair = 32 entries = 1 KB)

// round-to-nearest-even fp32 -> bf16 (finite values only)
static __device__ __forceinline__ short to_bf16(float x) {
    unsigned u = __float_as_uint(x);
    unsigned r = (u + 0x7FFFu + ((u >> 16) & 1u)) >> 16;
    return (short)r;
}

// Prep: pack codebook entries as 16 bf16 [e0..e7, -0.5*||e||^2, 0...] and
// z rows as 8 bf16; zero the loss slot.
__global__ __launch_bounds__(256) void vq_prep(
    const float* __restrict__ z, const float* __restrict__ cb,
    short8* __restrict__ cbb, short8* __restrict__ pka, float* __restrict__ out)
{
    int gid = blockIdx.x * 256 + threadIdx.x;
    if (gid == 0) out[NELEM] = 0.0f;
    if (gid < KCB) {
        const float4* p = (const float4*)(cb + (size_t)gid * 8);
        float4 a = p[0], b = p[1];
        float h = -0.5f * (a.x*a.x + a.y*a.y + a.z*a.z + a.w*a.w
                         + b.x*b.x + b.y*b.y + b.z*b.z + b.w*b.w);
        short8 lo = { to_bf16(a.x), to_bf16(a.y), to_bf16(a.z), to_bf16(a.w),
                      to_bf16(b.x), to_bf16(b.y), to_bf16(b.z), to_bf16(b.w) };
        short8 hi = { to_bf16(h), 0, 0, 0, 0, 0, 0, 0 };
        cbb[2 * gid]     = lo;
        cbb[2 * gid + 1] = hi;
    } else {
        int n = gid - KCB;
        int bb = n >> 12, hw = n & 4095;
        const float* zp = z + (size_t)bb * 32768 + hw;
        short8 v = { to_bf16(zp[0]),     to_bf16(zp[4096]),
                     to_bf16(zp[8192]),  to_bf16(zp[12288]),
                     to_bf16(zp[16384]), to_bf16(zp[20480]),
                     to_bf16(zp[24576]), to_bf16(zp[28672]) };
        pka[n] = v;
    }
}

#define WAITVM(n) asm volatile("s_waitcnt vmcnt(" #n ")" ::: "memory")

// Main: 512 blocks x 512 thr (8 waves), 64 rows/block. Wave w scans a private
// 1024-entry k-slice via a barrier-free global_load_lds ring (depth 4 pairs,
// counted vmcnt, never drained in-loop). LDS 2-way swizzled via pre-swizzled
// global source. Argmax = packed (score|inv-idx) + max3 over tile pairs.
__global__ __launch_bounds__(512, 6) void vq_main(
    const float* __restrict__ z, const float* __restrict__ cb,
    const short8* __restrict__ cbb, const short8* __restrict__ pka,
    float* __restrict__ out)
{
    __shared__ short8 ring[8][RING][64];   // 32 KB: wave-private rings
    __shared__ float  sbest[8][ROWS_PB];
    __shared__ float  lsum[8];

    const int tid  = threadIdx.x;
    const int lane = tid & 63;
    const int w    = tid >> 6;        // k-wave 0..7
    const int col  = lane & 15;
    const int g    = lane >> 4;

    const int row0 = blockIdx.x * ROWS_PB;

    // ---- A fragments: 4 row-tiles of 16; k-slots 0..7 = channels, 8 = 1.0 ----
    short8 af[4];
    #pragma unroll
    for (int f = 0; f < 4; ++f) {
        short8 v = {0, 0, 0, 0, 0, 0, 0, 0};
        if (g == 0)      v = pka[row0 + f * 16 + col];
        else if (g == 1) v[0] = (short)0x3F80;   // bf16(1.0) pairs with -0.5||e||^2
        af[f] = v;
    }

    const int kbase = w * 1024;
    const char* cbbase = (const char*)cbb + (size_t)kbase * 32;
    // source swizzle: LDS[x*16] gets global[x*16 ^ ((x&8)<<1)] (flip byte-bit4 by entry-bit2)
    const unsigned srcswz = ((unsigned)lane * 16u) ^ (((unsigned)lane & 8u) << 1);
    // read-side: half-select h = (g&1) ^ (col>>2 & 1); byte off within pair
    const int boff = col * 32 + (((g & 1) ^ ((col >> 2) & 1)) << 4);

    float best[4][4];
    #pragma unroll
    for (int f = 0; f < 4; ++f)
        #pragma unroll
        for (int r = 0; r < 4; ++r)
            best[f][r] = __uint_as_float(0xFF800000u);   // -inf

    const unsigned inv0 = (unsigned)(8191 - (kbase + col));
    const f32x4 zacc = {0.f, 0.f, 0.f, 0.f};

#define STAGE(p) __builtin_amdgcn_global_load_lds( \
        (const __attribute__((address_space(1))) void*)(cbbase + (size_t)(p) * 1024 + srcswz), \
        (__attribute__((address_space(3))) void*)&ring[w][(p) & 3][0], 16, 0, 0)

    // drain A-frag loads so our manual vmcnt counts only staging loads
    asm volatile("s_waitcnt vmcnt(0)" ::: "memory");
    STAGE(0); STAGE(1); STAGE(2); STAGE(3);

    // process tile pair: 32 entries, 8 MFMA, max3-merged packing
    auto comp2 = [&](const short8* base, unsigned iv0) {
        short8 b0 = *(const short8*)((const char*)base + boff);
        short8 b1 = *(const short8*)((const char*)base + boff + 512);
        unsigned iv1 = iv0 - 16u;
        #pragma unroll
        for (int f = 0; f < 4; ++f) {
            f32x4 a0 = __builtin_amdgcn_mfma_f32_16x16x32_bf16(af[f], b0, zacc, 0, 0, 0);
            f32x4 a1 = __builtin_amdgcn_mfma_f32_16x16x32_bf16(af[f], b1, zacc, 0, 0, 0);
            #pragma unroll
            for (int r = 0; r < 4; ++r) {
                float p0 = __uint_as_float((__float_as_uint(a0[r]) & 0xFFFFE000u) | iv0);
                float p1 = __uint_as_float((__float_as_uint(a1[r]) & 0xFFFFE000u) | iv1);
                best[f][r] = fmaxf(fmaxf(p0, p1), best[f][r]);   // v_max3_f32
            }
        }
    };

    #pragma unroll 4
    for (int p = 0; p < 28; ++p) {
        WAITVM(3);
        comp2(&ring[w][p & 3][0], inv0 - (unsigned)(p * 32));
        STAGE(p + 4);
    }
    WAITVM(3); comp2(&ring[w][0][0], inv0 - 28u * 32u);
    WAITVM(2); comp2(&ring[w][1][0], inv0 - 29u * 32u);
    WAITVM(1); comp2(&ring[w][2][0], inv0 - 30u * 32u);
    WAITVM(0); comp2(&ring[w][3][0], inv0 - 31u * 32u);

    // ---- cross-lane max within each 16-lane col group ----
    #pragma unroll
    for (int d = 1; d < 16; d <<= 1)
        #pragma unroll
        for (int f = 0; f < 4; ++f)
            #pragma unroll
            for (int r = 0; r < 4; ++r)
                best[f][r] = fmaxf(best[f][r], __shfl_xor(best[f][r], d));

    if (col == 0) {
        #pragma unroll
        for (int f = 0; f < 4; ++f)
            #pragma unroll
            for (int r = 0; r < 4; ++r)
                sbest[w][f * 16 + g * 4 + r] = best[f][r];   // row = g*4+r of tile f
    }
    __syncthreads();

    // ---- emit: 64 rows x 8 ch, one elem/thread ----
    const int pos = tid & 63;
    const int ch  = tid >> 6;
    float m = sbest[0][pos];
    #pragma unroll
    for (int kw = 1; kw < 8; ++kw) m = fmaxf(m, sbest[kw][pos]);
    const int k = 8191 - (int)(__float_as_uint(m) & 8191u);

    const int n = row0 + pos;
    const size_t o = ((size_t)(n >> 12)) * 32768 + (size_t)ch * 4096 + (size_t)(n & 4095);
    float ev = cb[(size_t)k * 8 + ch];
    float zz = z[o];
    out[o] = ev;
    float dd = ev - zz;
    float sq = dd * dd;
    #pragma unroll
    for (int off = 32; off > 0; off >>= 1) sq += __shfl_down(sq, off);
    if (lane == 0) lsum[w] = sq;
    __syncthreads();
    if (tid == 0) {
        float s = 0.f;
        #pragma unroll
        for (int kw = 0; kw < 8; ++kw) s += lsum[kw];
        atomicAdd(out + NELEM, s * (1.25f / (float)NELEM));
    }
}

extern "C" void kernel_launch(void* const* d_in, const int* in_sizes, int n_in,
                              void* d_out, int out_size, void* d_ws, size_t ws_size,
                              hipStream_t stream)
{
    const float* z  = (const float*)d_in[0];   // [8, 8, 64, 64] fp32
    const float* cb = (const float*)d_in[1];   // [8192, 8] fp32
    float* out = (float*)d_out;                // 262144 z_q + 1 loss
    short8* cbb = (short8*)d_ws;                       // 256 KB packed codebook
    short8* pka = (short8*)((char*)d_ws + 256 * 1024); // 512 KB packed z rows

    vq_prep<<<(KCB + NROWS) / 256, 256, 0, stream>>>(z, cb, cbb, pka, out);
    vq_main<<<NROWS / ROWS_PB, 512, 0, stream>>>(z, cb, cbb, pka, out);
}